// Round 3
// baseline (274.397 us; speedup 1.0000x reference)
//
#include <hip/hip_runtime.h>
#include <hip/hip_fp16.h>
#include <math.h>

#define NWAVE 8
#define OCD 24   // NWAVE*NIPS
#define CAP 96   // max pairs per atom bucket (Poisson lambda=50, P(>96)*20000 ~ 6e-4)

// 32B record: half u[0..2], pad, half cr[8] = cut*radial, int jn, pad
struct __align__(16) Rec {
    __half u[4];
    __half cr[8];
    int jn;
    int pad;
};

// ---------------- phase 1: rank pairs into buckets (4B scatter only) ----------------

__global__ __launch_bounds__(256) void scatter_kernel(
    const int* __restrict__ nl, int* __restrict__ cnt, int* __restrict__ perm, int npair) {
    int p = blockIdx.x * 256 + threadIdx.x;
    if (p >= npair) return;
    int i = nl[p];
    int rank = atomicAdd(&cnt[i], 1);
    if (rank < CAP) perm[i * CAP + rank] = p;
}

// ---------------- phase 2: build sorted records (gather reads, coalesced writes) ----

__global__ __launch_bounds__(256) void build_kernel(
    const int* __restrict__ nl, const float* __restrict__ cart,
    const float* __restrict__ shifts, const int* __restrict__ species,
    const float* __restrict__ rs, const float* __restrict__ inta,
    const int* __restrict__ cnt, const int* __restrict__ perm,
    Rec* __restrict__ rec, int numatom, int npair) {
    int s = blockIdx.x * 256 + threadIdx.x;
    if (s >= numatom * CAP) return;
    int a = s / CAP;
    int r = s - a * CAP;
    int e = cnt[a];
    e = e < CAP ? e : CAP;
    if (r >= e) return;
    int p = perm[s];
    int j = nl[npair + p];  // gather
    float sx = shifts[3 * p + 0], sy = shifts[3 * p + 1], sz = shifts[3 * p + 2];  // gather
    float dx = cart[3 * a + 0] - cart[3 * j + 0] - sx;
    float dy = cart[3 * a + 1] - cart[3 * j + 1] - sy;
    float dz = cart[3 * a + 2] - cart[3 * j + 2] - sz;
    float dist = sqrtf(dx * dx + dy * dy + dz * dz);
    float inv = 1.0f / dist;
    float c = 0.5f * __cosf(dist * 0.62831853071795864769f) + 0.5f;  // pi/CUTOFF
    float cut = c * c;
    int sj = species[j];
    Rec rc;
    rc.u[0] = __float2half(dx * inv);
    rc.u[1] = __float2half(dy * inv);
    rc.u[2] = __float2half(dz * inv);
    rc.u[3] = __float2half(0.f);
#pragma unroll
    for (int k = 0; k < 8; ++k) {
        float dd = dist - rs[sj * 8 + k];
        rc.cr[k] = __float2half(cut * __expf(-inta[sj * 8 + k] * dd * dd));
    }
    rc.jn = j;
    rc.pad = 0;
    int4* dst = (int4*)&rec[s];
    const int4* src = (const int4*)&rc;
    dst[0] = src[0];
    dst[1] = src[1];
}

// ---------------- per-atom orbit coeff ----------------

__global__ void init_oc_kernel(const float* __restrict__ params, const int* __restrict__ species,
                               float* __restrict__ oc, int numatom) {
    int idx = blockIdx.x * blockDim.x + threadIdx.x;
    if (idx >= numatom * OCD) return;
    int a = idx / OCD, d = idx - a * OCD;
    oc[idx] = params[species[a] * OCD + d];
}

__global__ void update_kernel(const float* __restrict__ density,
                              const float* __restrict__ W,    // 24x24
                              const float* __restrict__ emb,  // ntype x 24
                              const int* __restrict__ species,
                              float* __restrict__ oc, int numatom) {
    int idx = blockIdx.x * blockDim.x + threadIdx.x;
    if (idx >= numatom * OCD) return;
    int a = idx / OCD, d = idx - a * OCD;
    const float* dens = density + a * OCD;
    float s = emb[species[a] * OCD + d];
#pragma unroll
    for (int e = 0; e < OCD; ++e) s += dens[e] * W[e * OCD + d];
    oc[idx] = tanhf(s) + oc[idx];
}

// ---------------- obtain: one wave per atom, software-pipelined ----------------
// lane = pp*8 + m ; pp handles every-8th record of the bucket; m = wave channel.

__global__ __launch_bounds__(256) void obtain_kernel(
    const Rec* __restrict__ rec, const int* __restrict__ cnt,
    const float* __restrict__ oc, const float* __restrict__ hyp,  // 3*8*8 slice
    float* __restrict__ density,                                  // numatom x 24
    int numatom) {
    int wave = (int)((blockIdx.x * (size_t)blockDim.x + threadIdx.x) >> 6);
    if (wave >= numatom) return;
    int lane = threadIdx.x & 63;
    int m = lane & 7;
    int pp = lane >> 3;

    float hr[3][8];
#pragma unroll
    for (int ip = 0; ip < 3; ++ip)
#pragma unroll
        for (int k = 0; k < 8; ++k) hr[ip][k] = hyp[(ip * 8 + k) * 8 + m];

    float acc[13];
#pragma unroll
    for (int j = 0; j < 13; ++j) acc[j] = 0.f;

    int e = cnt[wave];
    e = e < CAP ? e : CAP;
    const int4* base = (const int4*)(rec + (size_t)wave * CAP);

    int p = pp;
    if (p < e) {
        int4 lo = base[2 * p];
        int4 hi = base[2 * p + 1];
        while (true) {
            int pn = p + 8;
            bool more = pn < e;
            int4 nlo, nhi;
            if (more) {  // prefetch next record
                nlo = base[2 * pn];
                nhi = base[2 * pn + 1];
            }
            // issue oc gathers early: jn is already in registers
            int jn = ((const int*)&hi)[2];
            const float* ocj = oc + jn * OCD;
            float o0 = ocj[m];
            float o1 = ocj[8 + m];
            float o2 = ocj[16 + m];
            const __half* hl = (const __half*)&lo;
            const __half* hh = (const __half*)&hi;
            float ux = __half2float(hl[0]);
            float uy = __half2float(hl[1]);
            float uz = __half2float(hl[2]);
            float cr[8];
#pragma unroll
            for (int k = 0; k < 4; ++k) cr[k] = __half2float(hl[4 + k]);
#pragma unroll
            for (int k = 0; k < 4; ++k) cr[4 + k] = __half2float(hh[k]);
            float rh0 = 0.f, rh1 = 0.f, rh2 = 0.f;
#pragma unroll
            for (int k = 0; k < 8; ++k) {
                rh0 += cr[k] * hr[0][k];
                rh1 += cr[k] * hr[1][k];
                rh2 += cr[k] * hr[2][k];
            }
            float t0 = rh0 * o0;
            float t1 = rh1 * o1;
            float t2 = rh2 * o2;
            acc[0] += t0;
            acc[1] += ux * t1;
            acc[2] += uy * t1;
            acc[3] += uz * t1;
            float vx = ux * t2, vy = uy * t2, vz = uz * t2;
            acc[4] += ux * vx;
            acc[5] += ux * vy;
            acc[6] += ux * vz;
            acc[7] += uy * vx;
            acc[8] += uy * vy;
            acc[9] += uy * vz;
            acc[10] += uz * vx;
            acc[11] += uz * vy;
            acc[12] += uz * vz;
            if (!more) break;
            p = pn;
            lo = nlo;
            hi = nhi;
        }
    }
#pragma unroll
    for (int j = 0; j < 13; ++j) {
        acc[j] += __shfl_xor(acc[j], 8);
        acc[j] += __shfl_xor(acc[j], 16);
        acc[j] += __shfl_xor(acc[j], 32);
    }
    if (pp == 0) {
        float d0 = acc[0] * acc[0];
        float d1 = acc[1] * acc[1] + acc[2] * acc[2] + acc[3] * acc[3];
        float d2 = 0.f;
#pragma unroll
        for (int j = 4; j < 13; ++j) d2 += acc[j] * acc[j];
        density[wave * OCD + m] = d0;
        density[wave * OCD + 8 + m] = d1;
        density[wave * OCD + 16 + m] = d2;
    }
}

// ---------------- launch ----------------

extern "C" void kernel_launch(void* const* d_in, const int* in_sizes, int n_in,
                              void* d_out, int out_size, void* d_ws, size_t ws_size,
                              hipStream_t stream) {
    const float* cart = (const float*)d_in[0];
    const float* shifts = (const float*)d_in[1];
    const float* rs = (const float*)d_in[2];
    const float* inta = (const float*)d_in[3];
    const float* params = (const float*)d_in[4];
    const float* hyper = (const float*)d_in[5];   // 3 x 3 x 8 x 8
    const float* ocW = (const float*)d_in[6];     // 2 x 24 x 24
    const float* ocEmb = (const float*)d_in[7];   // 2 x ntype x 24
    const int* nl = (const int*)d_in[8];          // 2 x npair
    const int* species = (const int*)d_in[9];

    int numatom = in_sizes[0] / 3;
    int npair = in_sizes[8] / 2;
    int ntype = in_sizes[2] / NWAVE;

    char* w = (char*)d_ws;
    Rec* rec = (Rec*)w;                                   // numatom*CAP*32B
    size_t rec_bytes = (size_t)numatom * CAP * sizeof(Rec);
    int* perm = (int*)(w + rec_bytes);                    // numatom*CAP*4B
    int* cnt = perm + (size_t)numatom * CAP;              // numatom*4B
    float* oc = (float*)(cnt + numatom);                  // numatom*24*4B
    float* density = (float*)d_out;

    const int tb = 256;
    hipMemsetAsync(cnt, 0, numatom * sizeof(int), stream);
    scatter_kernel<<<(npair + tb - 1) / tb, tb, 0, stream>>>(nl, cnt, perm, npair);
    build_kernel<<<(numatom * CAP + tb - 1) / tb, tb, 0, stream>>>(
        nl, cart, shifts, species, rs, inta, cnt, perm, rec, numatom, npair);
    init_oc_kernel<<<(numatom * OCD + tb - 1) / tb, tb, 0, stream>>>(params, species, oc, numatom);

    int obl = (int)(((size_t)numatom * 64 + tb - 1) / tb);  // 4 atoms (waves) per block
    obtain_kernel<<<obl, tb, 0, stream>>>(rec, cnt, oc, hyper + 0 * 192, density, numatom);
    for (int it = 0; it < 2; ++it) {
        update_kernel<<<(numatom * OCD + tb - 1) / tb, tb, 0, stream>>>(
            density, ocW + (size_t)it * OCD * OCD, ocEmb + (size_t)it * ntype * OCD, species, oc,
            numatom);
        obtain_kernel<<<obl, tb, 0, stream>>>(rec, cnt, oc, hyper + (size_t)(it + 1) * 192,
                                              density, numatom);
    }
}

// Round 4
// 259.572 us; speedup vs baseline: 1.0571x; 1.0571x over previous
//
#include <hip/hip_runtime.h>
#include <hip/hip_fp16.h>
#include <math.h>

#define NWAVE 8
#define OCD 24       // NWAVE*NIPS
#define ABITS 7
#define APB 128      // atoms per coarse bucket
#define BCAP 7168    // recs per bucket cap (mean ~6400 + 10 sigma)
#define NBUCK_MAX 512
#define PPT 8        // pairs per thread in binA

// 32B record: half u[3]+pad, half cr[8]=cut*radial, int jn, int ia (center atom)
struct __align__(16) Rec {
    __half u[4];
    __half cr[8];
    int jn;
    int ia;
};

// ---------------- binA: compute recs, coarse-bin into 128-atom buckets ----------------

__global__ __launch_bounds__(256) void binA_kernel(
    const int* __restrict__ nl, const float* __restrict__ cart,
    const float* __restrict__ shifts, const int* __restrict__ species,
    const float* __restrict__ rs, const float* __restrict__ inta,
    int* __restrict__ bucketCnt, Rec* __restrict__ coarse, int npair, int nbuck) {
    __shared__ int hist[NBUCK_MAX];
    __shared__ int cur[NBUCK_MAX];
    int tid = threadIdx.x;
    int wgbase = blockIdx.x * (256 * PPT);
    for (int b = tid; b < nbuck; b += 256) hist[b] = 0;
    __syncthreads();
#pragma unroll
    for (int k = 0; k < PPT; ++k) {
        int p = wgbase + k * 256 + tid;
        if (p < npair) atomicAdd(&hist[nl[p] >> ABITS], 1);
    }
    __syncthreads();
    for (int b = tid; b < nbuck; b += 256) {
        int n = hist[b];
        cur[b] = n ? atomicAdd(&bucketCnt[b], n) : 0;  // global base for this WG's run
    }
    __syncthreads();
#pragma unroll
    for (int k = 0; k < PPT; ++k) {
        int p = wgbase + k * 256 + tid;
        if (p >= npair) continue;
        int i = nl[p];
        int b = i >> ABITS;
        int slot = atomicAdd(&cur[b], 1);
        if (slot >= BCAP) continue;  // statistically impossible
        int j = nl[npair + p];
        float dx = cart[3 * i + 0] - cart[3 * j + 0] - shifts[3 * p + 0];
        float dy = cart[3 * i + 1] - cart[3 * j + 1] - shifts[3 * p + 1];
        float dz = cart[3 * i + 2] - cart[3 * j + 2] - shifts[3 * p + 2];
        float dist = sqrtf(dx * dx + dy * dy + dz * dz);
        float inv = 1.0f / dist;
        float c = 0.5f * __cosf(dist * 0.62831853071795864769f) + 0.5f;  // pi/CUTOFF
        float cut = c * c;
        int sj = species[j];
        Rec rc;
        rc.u[0] = __float2half(dx * inv);
        rc.u[1] = __float2half(dy * inv);
        rc.u[2] = __float2half(dz * inv);
        rc.u[3] = __float2half(0.f);
#pragma unroll
        for (int kk = 0; kk < 8; ++kk) {
            float dd = dist - rs[sj * 8 + kk];
            rc.cr[kk] = __float2half(cut * __expf(-inta[sj * 8 + kk] * dd * dd));
        }
        rc.jn = j;
        rc.ia = i;
        int4* dst = (int4*)&coarse[(size_t)b * BCAP + slot];
        const int4* src = (const int4*)&rc;
        dst[0] = src[0];
        dst[1] = src[1];
    }
}

// ---------------- binB: per-bucket fine sort -> compact CSR (L2-local writes) --------

__global__ __launch_bounds__(256) void binB_kernel(
    const int* __restrict__ bucketCnt, const Rec* __restrict__ coarse,
    Rec* __restrict__ recs, int* __restrict__ offs, int* __restrict__ cntA,
    int numatom, int nbuck) {
    __shared__ int ia[BCAP];
    __shared__ int hist[APB];
    __shared__ int pre[APB];
    __shared__ int scan[NBUCK_MAX];
    __shared__ int bbase_s;
    int b = blockIdx.x;
    int tid = threadIdx.x;
    for (int x = tid; x < nbuck; x += 256) {
        int c = bucketCnt[x];
        scan[x] = c < BCAP ? c : BCAP;
    }
    for (int a = tid; a < APB; a += 256) hist[a] = 0;
    __syncthreads();
    if (tid == 0) {
        int s = 0;
        for (int x = 0; x < b; ++x) s += scan[x];
        bbase_s = s;
    }
    int Cb = bucketCnt[b];
    Cb = Cb < BCAP ? Cb : BCAP;
    int aBase = b << ABITS;
    const int4* cb = (const int4*)(coarse + (size_t)b * BCAP);
    for (int t = tid; t < Cb; t += 256) {
        int i = ((const int*)&cb[2 * t + 1])[3];  // ia field
        int a = i - aBase;
        ia[t] = a;
        atomicAdd(&hist[a], 1);
    }
    __syncthreads();
    if (tid == 0) {
        int s = 0;
        for (int a = 0; a < APB; ++a) {
            pre[a] = s;
            s += hist[a];
        }
    }
    __syncthreads();
    int bbase = bbase_s;
    int wa = numatom - aBase;
    wa = wa < APB ? wa : APB;
    for (int a = tid; a < wa; a += 256) {
        offs[aBase + a] = bbase + pre[a];
        cntA[aBase + a] = hist[a];
    }
    for (int a = tid; a < APB; a += 256) hist[a] = pre[a];  // hist becomes cursor
    __syncthreads();
    for (int t = tid; t < Cb; t += 256) {
        int a = ia[t];
        int slot = atomicAdd(&hist[a], 1);
        int4 lo = cb[2 * t];       // L2-hot (fetched in pass 1)
        int4 hi = cb[2 * t + 1];
        int4* dst = (int4*)&recs[(size_t)bbase + slot];
        dst[0] = lo;
        dst[1] = hi;
    }
}

// ---------------- per-atom orbit coeff ----------------

__global__ void init_oc_kernel(const float* __restrict__ params, const int* __restrict__ species,
                               float* __restrict__ oc, int numatom) {
    int idx = blockIdx.x * blockDim.x + threadIdx.x;
    if (idx >= numatom * OCD) return;
    int a = idx / OCD, d = idx - a * OCD;
    oc[idx] = params[species[a] * OCD + d];
}

__global__ void update_kernel(const float* __restrict__ density,
                              const float* __restrict__ W, const float* __restrict__ emb,
                              const int* __restrict__ species, float* __restrict__ oc,
                              int numatom) {
    int idx = blockIdx.x * blockDim.x + threadIdx.x;
    if (idx >= numatom * OCD) return;
    int a = idx / OCD, d = idx - a * OCD;
    const float* dens = density + a * OCD;
    float s = emb[species[a] * OCD + d];
#pragma unroll
    for (int e = 0; e < OCD; ++e) s += dens[e] * W[e * OCD + d];
    oc[idx] = tanhf(s) + oc[idx];
}

// ---------------- obtain: 2 warps per atom, LDS combine ----------------
// warp lane: m = lane&7 (wave channel), pp = lane>>3 (rec sub-stream).
// warp handles recs s + half*8 + pp, stride 16.

__global__ __launch_bounds__(256) void obtain_kernel(
    const Rec* __restrict__ recs, const int* __restrict__ offs,
    const int* __restrict__ cntA, const float* __restrict__ oc,
    const float* __restrict__ hyp, float* __restrict__ density, int numatom) {
    __shared__ float part[2][2][13][8];
    int tid = threadIdx.x;
    int warp = tid >> 6;
    int slot = warp >> 1;
    int half = warp & 1;
    int atom = blockIdx.x * 2 + slot;
    int lane = tid & 63;
    int m = lane & 7;
    int pp = lane >> 3;

    float hr[3][8];
#pragma unroll
    for (int ip = 0; ip < 3; ++ip)
#pragma unroll
        for (int k = 0; k < 8; ++k) hr[ip][k] = hyp[(ip * 8 + k) * 8 + m];

    float acc[13];
#pragma unroll
    for (int j = 0; j < 13; ++j) acc[j] = 0.f;

    int s = 0, e = 0;
    if (atom < numatom) {
        s = offs[atom];
        e = s + cntA[atom];
    }
    const int4* base = (const int4*)recs;
    int p = s + half * 8 + pp;
    if (p < e) {
        int4 lo = base[2 * p];
        int4 hi = base[2 * p + 1];
        while (true) {
            int pn = p + 16;
            bool more = pn < e;
            int4 nlo, nhi;
            if (more) {
                nlo = base[2 * pn];
                nhi = base[2 * pn + 1];
            }
            int jn = ((const int*)&hi)[2];
            const float* ocj = oc + jn * OCD;
            float o0 = ocj[m];
            float o1 = ocj[8 + m];
            float o2 = ocj[16 + m];
            const __half* hl = (const __half*)&lo;
            const __half* hh = (const __half*)&hi;
            float ux = __half2float(hl[0]);
            float uy = __half2float(hl[1]);
            float uz = __half2float(hl[2]);
            float cr[8];
#pragma unroll
            for (int k = 0; k < 4; ++k) cr[k] = __half2float(hl[4 + k]);
#pragma unroll
            for (int k = 0; k < 4; ++k) cr[4 + k] = __half2float(hh[k]);
            float rh0 = 0.f, rh1 = 0.f, rh2 = 0.f;
#pragma unroll
            for (int k = 0; k < 8; ++k) {
                rh0 += cr[k] * hr[0][k];
                rh1 += cr[k] * hr[1][k];
                rh2 += cr[k] * hr[2][k];
            }
            float t0 = rh0 * o0;
            float t1 = rh1 * o1;
            float t2 = rh2 * o2;
            acc[0] += t0;
            acc[1] += ux * t1;
            acc[2] += uy * t1;
            acc[3] += uz * t1;
            float vx = ux * t2, vy = uy * t2, vz = uz * t2;
            acc[4] += ux * vx;
            acc[5] += ux * vy;
            acc[6] += ux * vz;
            acc[7] += uy * vx;
            acc[8] += uy * vy;
            acc[9] += uy * vz;
            acc[10] += uz * vx;
            acc[11] += uz * vy;
            acc[12] += uz * vz;
            if (!more) break;
            p = pn;
            lo = nlo;
            hi = nhi;
        }
    }
#pragma unroll
    for (int j = 0; j < 13; ++j) {
        acc[j] += __shfl_xor(acc[j], 8);
        acc[j] += __shfl_xor(acc[j], 16);
        acc[j] += __shfl_xor(acc[j], 32);
    }
    if (pp == 0) {
#pragma unroll
        for (int j = 0; j < 13; ++j) part[slot][half][j][m] = acc[j];
    }
    __syncthreads();
    if (half == 0 && pp == 0 && atom < numatom) {
        float v[13];
#pragma unroll
        for (int j = 0; j < 13; ++j) v[j] = part[slot][0][j][m] + part[slot][1][j][m];
        float d0 = v[0] * v[0];
        float d1 = v[1] * v[1] + v[2] * v[2] + v[3] * v[3];
        float d2 = 0.f;
#pragma unroll
        for (int j = 4; j < 13; ++j) d2 += v[j] * v[j];
        density[atom * OCD + m] = d0;
        density[atom * OCD + 8 + m] = d1;
        density[atom * OCD + 16 + m] = d2;
    }
}

// ---------------- launch ----------------

extern "C" void kernel_launch(void* const* d_in, const int* in_sizes, int n_in,
                              void* d_out, int out_size, void* d_ws, size_t ws_size,
                              hipStream_t stream) {
    const float* cart = (const float*)d_in[0];
    const float* shifts = (const float*)d_in[1];
    const float* rs = (const float*)d_in[2];
    const float* inta = (const float*)d_in[3];
    const float* params = (const float*)d_in[4];
    const float* hyper = (const float*)d_in[5];   // 3 x 3 x 8 x 8
    const float* ocW = (const float*)d_in[6];     // 2 x 24 x 24
    const float* ocEmb = (const float*)d_in[7];   // 2 x ntype x 24
    const int* nl = (const int*)d_in[8];          // 2 x npair
    const int* species = (const int*)d_in[9];

    int numatom = in_sizes[0] / 3;
    int npair = in_sizes[8] / 2;
    int ntype = in_sizes[2] / NWAVE;
    int nbuck = (numatom + APB - 1) >> ABITS;

    char* w = (char*)d_ws;
    Rec* coarse = (Rec*)w;
    size_t coarse_bytes = (size_t)nbuck * BCAP * sizeof(Rec);
    Rec* recs = (Rec*)(w + coarse_bytes);
    size_t recs_bytes = (size_t)npair * sizeof(Rec);
    int* bucketCnt = (int*)(w + coarse_bytes + recs_bytes);
    int* offs = bucketCnt + nbuck;
    int* cntA = offs + numatom;
    float* oc = (float*)(cntA + numatom);
    float* density = (float*)d_out;

    const int tb = 256;
    hipMemsetAsync(bucketCnt, 0, nbuck * sizeof(int), stream);
    binA_kernel<<<(npair + tb * PPT - 1) / (tb * PPT), tb, 0, stream>>>(
        nl, cart, shifts, species, rs, inta, bucketCnt, coarse, npair, nbuck);
    binB_kernel<<<nbuck, tb, 0, stream>>>(bucketCnt, coarse, recs, offs, cntA, numatom, nbuck);
    init_oc_kernel<<<(numatom * OCD + tb - 1) / tb, tb, 0, stream>>>(params, species, oc, numatom);

    int obl = (numatom + 1) / 2;
    obtain_kernel<<<obl, tb, 0, stream>>>(recs, offs, cntA, oc, hyper + 0 * 192, density, numatom);
    for (int it = 0; it < 2; ++it) {
        update_kernel<<<(numatom * OCD + tb - 1) / tb, tb, 0, stream>>>(
            density, ocW + (size_t)it * OCD * OCD, ocEmb + (size_t)it * ntype * OCD, species, oc,
            numatom);
        obtain_kernel<<<obl, tb, 0, stream>>>(recs, offs, cntA, oc, hyper + (size_t)(it + 1) * 192,
                                              density, numatom);
    }
}